// Round 1
// baseline (252.377 us; speedup 1.0000x reference)
//
#include <hip/hip_runtime.h>

#define Bdim 64
#define Tdim 2048
#define Fdim 256
#define TAIL 256      // truncated EMA window: 0.8^256 ~ 1e-25, far below fp32 noise
#define NCH 8
#define CHT 32        // TAIL / NCH

#define BM 64
#define BK 32         // 8 K-chunks of 32; small chunks let the 2-deep pipeline hide HBM latency
#define NCHUNK 8      // Fdim / BK

typedef __bf16 bf16x8 __attribute__((ext_vector_type(8)));
typedef float f32x16 __attribute__((ext_vector_type(16)));
typedef unsigned short u16x8 __attribute__((ext_vector_type(8)));

__device__ __forceinline__ unsigned short bf16_rne(float f) {
  unsigned int u = __float_as_uint(f);
  u += 0x7FFFu + ((u >> 16) & 1u);
  return (unsigned short)(u >> 16);
}

// Merged prep: blocks [0,256) transpose W -> Wt bf16 ; blocks [256,768) EMA partial sums.
__global__ void prep(const float* __restrict__ x, const float* __restrict__ W,
                     unsigned short* __restrict__ Wt, float* __restrict__ part) {
  int blk = blockIdx.x;
  if (blk < Fdim) {
    int i = blk * 256 + threadIdx.x;   // i = g*256 + f
    int g = i >> 8, f = i & 255;
    Wt[i] = bf16_rne(W[f * Fdim + g]);
  } else {
    int j = blk - Fdim;                // 0..511
    int b = j & 63, c = j >> 6;
    int f = threadIdx.x;
    int t0 = Tdim - TAIL + c * CHT;
    // w(t) = 0.2 * 0.8^(T-1-t); iterate upward multiplying by 1.25 (exact in fp32)
    float w = 0.2f * exp2f((float)(Tdim - 1 - t0) * -0.32192809488736235f);
    const float* xp = x + ((size_t)b * Tdim + t0) * Fdim + f;
    float s = 0.f;
#pragma unroll
    for (int q = 0; q < CHT; ++q) {
      s += w * xp[(size_t)q * Fdim];
      w *= 1.25f;
    }
    part[(c * Bdim + b) * Fdim + f] = s;
  }
}

// out[row][n] = sum_k x[row][k]*W[k][n] + bias[n] + lastref[b][n]
// BM=64 rows/block, BN=256 full (x read exactly once), BK=32 x 8 chunks.
// Pipeline: A prefetched 2 chunks ahead (regs), B 1 chunk ahead (regs),
// double-buffered LDS, ONE barrier per chunk. LDS rows 64 B, XOR slot swizzle
// (slot ^= row&3) -> <=2-way bank aliasing on ds_read_b128/ds_write_b128 (free, m136).
__global__ __launch_bounds__(256, 3)
void gemm_fused(const float* __restrict__ x, const unsigned short* __restrict__ Wt,
                const float* __restrict__ bias, const float* __restrict__ part,
                float* __restrict__ out) {
  __shared__ unsigned short Abuf[2][BM * BK];     // 2 x 4 KB
  __shared__ unsigned short Bbuf[2][Fdim * BK];   // 2 x 16 KB
  __shared__ float lref[Fdim];                    // 1 KB  -> 41 KB total, 3 blocks/CU

  const int tid = threadIdx.x;
  const int blk = blockIdx.x;            // 0..2047
  const int b = blk >> 5;                // 32 row-tiles per batch
  const size_t row0 = (size_t)blk * BM;

  const int wave = tid >> 6;             // n-position: wave covers 64 cols x 64 rows
  const int lane = tid & 63;
  const int lm = lane & 31;
  const int half = lane >> 5;

  {  // lastref[b][n] + bias[n], one n per thread
    float s = bias[tid];
#pragma unroll
    for (int c = 0; c < NCH; ++c) s += part[(c * Bdim + b) * Fdim + tid];
    lref[tid] = s;
  }

  // A staging map: thread -> (row ar, 8-float granule ag); 4 lanes = 128 B coalesced
  const int ar = tid >> 2;
  const int ag = tid & 3;
  const int aoff = ar * BK + ((ag ^ (ar & 3)) << 3);   // swizzled ushort index
  const float* asrc = x + (row0 + ar) * Fdim + ag * 8;

  // B staging map: 4 rounds p, row n = p*64 + bn, granule bg
  const int bn = tid >> 2;
  const int bg = tid & 3;
  const unsigned short* bsrc = Wt + (size_t)bn * Fdim + bg * 8;
  const int boff = bn * BK + ((bg ^ (bn & 3)) << 3);

  f32x16 acc[2][2] = {};       // [m-subtile][n-subtile], 32x32 each
  float4 Ar[2][2];             // 2-deep A prefetch (chunk k -> set k&1)
  u16x8 br0, br1, br2, br3;    // 1-deep B prefetch

  // ---- prologue: stage chunk 0, issue chunk-1 A loads ----
  Ar[0][0] = *(const float4*)(asrc);
  Ar[0][1] = *(const float4*)(asrc + 4);
  br0 = *(const u16x8*)(bsrc + 0 * 64 * Fdim);
  br1 = *(const u16x8*)(bsrc + 1 * 64 * Fdim);
  br2 = *(const u16x8*)(bsrc + 2 * 64 * Fdim);
  br3 = *(const u16x8*)(bsrc + 3 * 64 * Fdim);
  {
    float4 v0 = Ar[0][0], v1 = Ar[0][1];
    u16x8 w;
    w[0] = bf16_rne(v0.x); w[1] = bf16_rne(v0.y);
    w[2] = bf16_rne(v0.z); w[3] = bf16_rne(v0.w);
    w[4] = bf16_rne(v1.x); w[5] = bf16_rne(v1.y);
    w[6] = bf16_rne(v1.z); w[7] = bf16_rne(v1.w);
    *(u16x8*)&Abuf[0][aoff] = w;
  }
  *(u16x8*)&Bbuf[0][boff + 0 * 64 * BK] = br0;
  *(u16x8*)&Bbuf[0][boff + 1 * 64 * BK] = br1;
  *(u16x8*)&Bbuf[0][boff + 2 * 64 * BK] = br2;
  *(u16x8*)&Bbuf[0][boff + 3 * 64 * BK] = br3;
  Ar[1][0] = *(const float4*)(asrc + BK);
  Ar[1][1] = *(const float4*)(asrc + BK + 4);
  __syncthreads();

  // ---- main loop: one barrier per chunk ----
#pragma unroll
  for (int c = 0; c < NCHUNK; ++c) {
    const int cur = c & 1, nxt = cur ^ 1;
    if (c + 2 < NCHUNK) {               // A(c+2) -> regs (consumed next iter: full-iter latency gap)
      const float* s4 = asrc + (c + 2) * BK;
      Ar[cur][0] = *(const float4*)(s4);
      Ar[cur][1] = *(const float4*)(s4 + 4);
    }
    if (c + 1 < NCHUNK) {               // B(c+1) -> regs (L2-resident, hidden under MFMA)
      const unsigned short* bs = bsrc + (c + 1) * BK;
      br0 = *(const u16x8*)(bs + 0 * 64 * Fdim);
      br1 = *(const u16x8*)(bs + 1 * 64 * Fdim);
      br2 = *(const u16x8*)(bs + 2 * 64 * Fdim);
      br3 = *(const u16x8*)(bs + 3 * 64 * Fdim);
    }
#pragma unroll
    for (int s = 0; s < 2; ++s) {
      const int G = 2 * s + half;                   // logical 8-elem k-granule
      const int sw = ((G ^ (lm & 3)) << 3);         // physical (swizzled) slot
      bf16x8 a0 = *(const bf16x8*)&Abuf[cur][lm * BK + sw];
      bf16x8 a1 = *(const bf16x8*)&Abuf[cur][(32 + lm) * BK + sw];
      bf16x8 b0 = *(const bf16x8*)&Bbuf[cur][(wave * 64 + lm) * BK + sw];
      bf16x8 b1 = *(const bf16x8*)&Bbuf[cur][(wave * 64 + 32 + lm) * BK + sw];
      acc[0][0] = __builtin_amdgcn_mfma_f32_32x32x16_bf16(a0, b0, acc[0][0], 0, 0, 0);
      acc[0][1] = __builtin_amdgcn_mfma_f32_32x32x16_bf16(a0, b1, acc[0][1], 0, 0, 0);
      acc[1][0] = __builtin_amdgcn_mfma_f32_32x32x16_bf16(a1, b0, acc[1][0], 0, 0, 0);
      acc[1][1] = __builtin_amdgcn_mfma_f32_32x32x16_bf16(a1, b1, acc[1][1], 0, 0, 0);
    }
    if (c + 1 < NCHUNK) {               // write stage c+1 into the other buffer
      float4 v0 = Ar[nxt][0], v1 = Ar[nxt][1];
      u16x8 w;
      w[0] = bf16_rne(v0.x); w[1] = bf16_rne(v0.y);
      w[2] = bf16_rne(v0.z); w[3] = bf16_rne(v0.w);
      w[4] = bf16_rne(v1.x); w[5] = bf16_rne(v1.y);
      w[6] = bf16_rne(v1.z); w[7] = bf16_rne(v1.w);
      *(u16x8*)&Abuf[nxt][aoff] = w;
      *(u16x8*)&Bbuf[nxt][boff + 0 * 64 * BK] = br0;
      *(u16x8*)&Bbuf[nxt][boff + 1 * 64 * BK] = br1;
      *(u16x8*)&Bbuf[nxt][boff + 2 * 64 * BK] = br2;
      *(u16x8*)&Bbuf[nxt][boff + 3 * 64 * BK] = br3;
      __syncthreads();
    }
  }

  // epilogue: C/D layout col=lane&31, row=(r&3)+8*(r>>2)+4*(lane>>5)  [m74/m101]
  float* op = out + row0 * Fdim;
  const int rbase = 4 * half;
#pragma unroll
  for (int i = 0; i < 2; ++i) {
#pragma unroll
    for (int j = 0; j < 2; ++j) {
      int n = wave * 64 + j * 32 + lm;
      float lb = lref[n];
#pragma unroll
      for (int r = 0; r < 16; ++r) {
        int rowi = i * 32 + (r & 3) + 8 * (r >> 2) + rbase;
        op[(size_t)rowi * Fdim + n] = acc[i][j][r] + lb;
      }
    }
  }
}

extern "C" void kernel_launch(void* const* d_in, const int* in_sizes, int n_in,
                              void* d_out, int out_size, void* d_ws, size_t ws_size,
                              hipStream_t stream) {
  const float* x = (const float*)d_in[0];
  const float* W = (const float*)d_in[1];
  const float* bias = (const float*)d_in[2];
  float* out = (float*)d_out;

  unsigned short* Wt = (unsigned short*)d_ws;                                    // 128 KB
  float* part = (float*)((char*)d_ws + Fdim * Fdim * sizeof(unsigned short));    // 512 KB

  prep<<<Fdim + Bdim * NCH, 256, 0, stream>>>(x, W, Wt, part);
  gemm_fused<<<(Bdim * Tdim) / BM, 256, 0, stream>>>(x, Wt, bias, part, out);
}

// Round 3
// 247.038 us; speedup vs baseline: 1.0216x; 1.0216x over previous
//
#include <hip/hip_runtime.h>

#define Bdim 64
#define Tdim 2048
#define Fdim 256
#define TAIL 256      // truncated EMA window: 0.8^256 ~ 1e-25, far below fp32 noise
#define NCH 8
#define CHT 32        // TAIL / NCH

#define BM 64
#define BK 32         // 8 K-chunks of 32
#define NCHUNK 8      // Fdim / BK

typedef __bf16 bf16x8 __attribute__((ext_vector_type(8)));
typedef float f32x16 __attribute__((ext_vector_type(16)));
typedef unsigned short u16x8 __attribute__((ext_vector_type(8)));

__device__ __forceinline__ unsigned short bf16_rne(float f) {
  unsigned int u = __float_as_uint(f);
  u += 0x7FFFu + ((u >> 16) & 1u);
  return (unsigned short)(u >> 16);
}

// Merged prep:
//  blocks [0,256):   W fp32 -> Wf bf16 in FRAGMENT order.
//    Wf index o = (w*32 + c*4 + s*2 + which)*512 + lane*8 + e  holds
//    bf16(W[k][n]) with n = w*64 + which*32 + (lane&31),
//                       k = c*32 + (2*s + (lane>>5))*8 + e.
//    => every gemm B-fragment load is a coalesced 16B/lane dwordx4 stream.
//  blocks [256,768): EMA partial sums over t-chunks.
__global__ void prep(const float* __restrict__ x, const float* __restrict__ W,
                     unsigned short* __restrict__ Wf, float* __restrict__ part) {
  int blk = blockIdx.x;
  if (blk < Fdim) {
    int o = blk * 256 + threadIdx.x;
    int e = o & 7, lane = (o >> 3) & 63, wh = (o >> 9) & 1, s = (o >> 10) & 1;
    int c = (o >> 11) & 7, w = o >> 14;
    int n = w * 64 + wh * 32 + (lane & 31);
    int k = c * 32 + (2 * s + (lane >> 5)) * 8 + e;
    Wf[o] = bf16_rne(W[k * Fdim + n]);
  } else {
    int j = blk - Fdim;                // 0..511
    int b = j & 63, c = j >> 6;
    int f = threadIdx.x;
    int t0 = Tdim - TAIL + c * CHT;
    // w(t) = 0.2 * 0.8^(T-1-t); iterate upward multiplying by 1.25 (exact in fp32)
    float w = 0.2f * exp2f((float)(Tdim - 1 - t0) * -0.32192809488736235f);
    const float* xp = x + ((size_t)b * Tdim + t0) * Fdim + f;
    float s = 0.f;
#pragma unroll
    for (int q = 0; q < CHT; ++q) {
      s += w * xp[(size_t)q * Fdim];
      w *= 1.25f;
    }
    part[(c * Bdim + b) * Fdim + f] = s;
  }
}

// out[row][n] = sum_k x[row][k]*W[k][n] + bias[n] + lastref[b][n]
// A staged in LDS in MFMA FRAGMENT ORDER: Afrag[f][dl][0..7], f = i*2+s.
//   All 4 waves need identical A fragments (waves split n, share m).
//   Staging wave w loads rows (w>>1)*32+(l&31), cols ((w&1)*2+(l>>5))*8 and
//   writes to tid*16 B  -> lane-linear, ZERO bank conflicts.
//   Fragment reads are (f*64+l)*16 B -> lane-linear, ZERO bank conflicts.
// B (zero cross-wave reuse) read DIRECTLY from Wf (L2-hot, fragment-order,
// coalesced 16B/lane), refilled in regs right after use — no LDS, no barrier.
// 2-deep A reg prefetch, double-buffered LDS, one barrier per chunk.
__global__ __launch_bounds__(256, 4)
void gemm_fused(const float* __restrict__ x, const unsigned short* __restrict__ Wf,
                const float* __restrict__ bias, const float* __restrict__ part,
                float* __restrict__ out) {
  __shared__ unsigned short Abuf[2][4 * 64 * 8];   // 2 x 4 KB, fragment-order
  __shared__ float lref[Fdim];                     // 1 KB -> 9216 B total

  const int tid = threadIdx.x;
  const int blk = blockIdx.x;            // 0..2047
  const int b = blk >> 5;
  const size_t row0 = (size_t)blk * BM;

  const int wave = tid >> 6;             // n-position: wave covers 64 cols x 64 rows
  const int lane = tid & 63;
  const int lm = lane & 31;
  const int half = lane >> 5;

  {  // lastref[b][n] + bias[n], one n per thread
    float s = bias[tid];
#pragma unroll
    for (int c = 0; c < NCH; ++c) s += part[(c * Bdim + b) * Fdim + tid];
    lref[tid] = s;
  }

  // A staging: wave w owns fragment f=w (i = w>>1 m-subtile, s = w&1 k-half).
  // lane l: row (w>>1)*32 + (l&31), col ((w&1)*2 + (l>>5))*8. Dest = tid*8 ushorts.
  const int srow = (wave >> 1) * 32 + lm;
  const int scol = ((wave & 1) * 2 + half) * 8;
  const float* asrc = x + (row0 + srow) * Fdim + scol;
  const int adst = tid * 8;

  // B fragment stream base for this wave/lane
  const unsigned short* bsrc = Wf + (size_t)wave * (32 * 512) + lane * 8;

  f32x16 acc[2][2] = {};       // [m-subtile][n-subtile], 32x32 each
  float4 Ar[2][2];             // 2-deep A prefetch (chunk k -> slot k&1)
  bf16x8 Bf[2][2];             // current chunk's B fragments [s][which]

  // ---- prologue ----
  Ar[0][0] = *(const float4*)asrc;
  Ar[0][1] = *(const float4*)(asrc + 4);
  Bf[0][0] = *(const bf16x8*)(bsrc + 0 * 512);
  Bf[0][1] = *(const bf16x8*)(bsrc + 1 * 512);
  Bf[1][0] = *(const bf16x8*)(bsrc + 2 * 512);
  Bf[1][1] = *(const bf16x8*)(bsrc + 3 * 512);
  {
    float4 v0 = Ar[0][0], v1 = Ar[0][1];
    u16x8 w;
    w[0] = bf16_rne(v0.x); w[1] = bf16_rne(v0.y);
    w[2] = bf16_rne(v0.z); w[3] = bf16_rne(v0.w);
    w[4] = bf16_rne(v1.x); w[5] = bf16_rne(v1.y);
    w[6] = bf16_rne(v1.z); w[7] = bf16_rne(v1.w);
    *(u16x8*)&Abuf[0][adst] = w;
  }
  Ar[1][0] = *(const float4*)(asrc + BK);
  Ar[1][1] = *(const float4*)(asrc + BK + 4);
  __syncthreads();

  // ---- main loop: one barrier per chunk ----
#pragma unroll
  for (int c = 0; c < NCHUNK; ++c) {
    const int cur = c & 1, nxt = cur ^ 1;
    if (c + 2 < NCHUNK) {                // A(c+2) -> regs (slot freed last iter)
      const float* s4 = asrc + (c + 2) * BK;
      Ar[cur][0] = *(const float4*)s4;
      Ar[cur][1] = *(const float4*)(s4 + 4);
    }
#pragma unroll
    for (int s = 0; s < 2; ++s) {
      // fragment reads: lane-linear, conflict-free
      bf16x8 a0 = *(const bf16x8*)&Abuf[cur][(s * 64 + lane) * 8];        // i=0
      bf16x8 a1 = *(const bf16x8*)&Abuf[cur][((2 + s) * 64 + lane) * 8];  // i=1
      acc[0][0] = __builtin_amdgcn_mfma_f32_32x32x16_bf16(a0, Bf[s][0], acc[0][0], 0, 0, 0);
      acc[0][1] = __builtin_amdgcn_mfma_f32_32x32x16_bf16(a0, Bf[s][1], acc[0][1], 0, 0, 0);
      acc[1][0] = __builtin_amdgcn_mfma_f32_32x32x16_bf16(a1, Bf[s][0], acc[1][0], 0, 0, 0);
      acc[1][1] = __builtin_amdgcn_mfma_f32_32x32x16_bf16(a1, Bf[s][1], acc[1][1], 0, 0, 0);
      if (c + 1 < NCHUNK) {              // refill Bf[s] with chunk c+1 (after use)
        const unsigned short* bs = bsrc + (c + 1) * (4 * 512) + s * 1024;
        Bf[s][0] = *(const bf16x8*)bs;
        Bf[s][1] = *(const bf16x8*)(bs + 512);
      }
    }
    if (c + 1 < NCHUNK) {                // cvt + write A(c+1), single barrier
      float4 v0 = Ar[nxt][0], v1 = Ar[nxt][1];
      u16x8 w;
      w[0] = bf16_rne(v0.x); w[1] = bf16_rne(v0.y);
      w[2] = bf16_rne(v0.z); w[3] = bf16_rne(v0.w);
      w[4] = bf16_rne(v1.x); w[5] = bf16_rne(v1.y);
      w[6] = bf16_rne(v1.z); w[7] = bf16_rne(v1.w);
      *(u16x8*)&Abuf[nxt][adst] = w;
      __syncthreads();
    }
  }

  // epilogue: C/D layout col=lane&31, row=(r&3)+8*(r>>2)+4*(lane>>5)  [m74/m101]
  float* op = out + row0 * Fdim;
  const int rbase = 4 * half;
#pragma unroll
  for (int i = 0; i < 2; ++i) {
#pragma unroll
    for (int j = 0; j < 2; ++j) {
      int n = wave * 64 + j * 32 + lm;
      float lb = lref[n];
#pragma unroll
      for (int r = 0; r < 16; ++r) {
        int rowi = i * 32 + (r & 3) + 8 * (r >> 2) + rbase;
        op[(size_t)rowi * Fdim + n] = acc[i][j][r] + lb;
      }
    }
  }
}

extern "C" void kernel_launch(void* const* d_in, const int* in_sizes, int n_in,
                              void* d_out, int out_size, void* d_ws, size_t ws_size,
                              hipStream_t stream) {
  const float* x = (const float*)d_in[0];
  const float* W = (const float*)d_in[1];
  const float* bias = (const float*)d_in[2];
  float* out = (float*)d_out;

  unsigned short* Wf = (unsigned short*)d_ws;                                    // 128 KB
  float* part = (float*)((char*)d_ws + Fdim * Fdim * sizeof(unsigned short));    // 512 KB

  prep<<<Fdim + Bdim * NCH, 256, 0, stream>>>(x, W, Wf, part);
  gemm_fused<<<(Bdim * Tdim) / BM, 256, 0, stream>>>(x, Wf, bias, part, out);
}